// Round 8
// baseline (218.295 us; speedup 1.0000x reference)
//
#include <hip/hip_runtime.h>

#define NQ 2048
#define NT 131072
#define DD 64
#define MM 1024
#define NBUCK 512          // coarse buckets: v >> 8
#define BCAP 4608          // per-bucket capacity (mean 3937 over 508 live buckets; +10 sigma)
#define CHUNK 4096         // edges per bin block

// LESSONS (measured): r2 global-atomic CSR scatter: 176us, 155MB writes (XCD
// coherence + line write-allocate). r3 per-edge LDS ds_add scatter: 690us
// (LDS atomic pipe serializes). r4 fp16 gathers: -13%. r6 split: row phase
// alone = 93.5us of the 96us fused bucket (sort ~ few us fused); bin_yq
// ~90-105us co-equal bottleneck. r7: 8-lane groups halve per-edge issue.
// r7 bench was an infra failure (container), not a kernel failure — resubmit.

typedef __attribute__((ext_vector_type(2))) _Float16 h2;

#if defined(__has_builtin)
#if __has_builtin(__builtin_amdgcn_fdot2)
#define HAVE_FDOT2 1
#endif
#endif

__device__ __forceinline__ float fdot2(h2 a, h2 b, float c) {
#ifdef HAVE_FDOT2
    return __builtin_amdgcn_fdot2(a, b, c, false);
#else
    return fmaf((float)a.x, (float)b.x, fmaf((float)a.y, (float)b.y, c));
#endif
}

// YX16[u]: 256-half (512B) row. Halves [0..127]: 8 granules of 16 halves
// {ya[8s..8s+7], yb[8s..8s+7]} (s = 0..7) -> lane l8 loads 2x dwordx4 for both
// score fragments. Halves [128..191]: xq16. [192..255]: pad.
__global__ __launch_bounds__(1024) void bin_yq_kernel(
        const int* __restrict__ u_idx, const int* __restrict__ v_idx,
        int* __restrict__ gcurP, unsigned* __restrict__ gbuf,
        const float* __restrict__ Xq,
        const float* __restrict__ Wa, const float* __restrict__ Wb,
        _Float16* __restrict__ YX16,
        float* __restrict__ outXq, int E) {
    __shared__ unsigned stage[CHUNK];
    __shared__ int hist[NBUCK], off[NBUCK], base[NBUCK], cur[NBUCK];
    int tid = threadIdx.x;
    int nchunks = (E + CHUNK - 1) / CHUNK;

    if (blockIdx.x >= nchunks) {        // ---- yq role ----
        int r = (blockIdx.x - nchunks) * 16 + (tid >> 6);
        int j = tid & 63;
        float sa = 0.f, sb = 0.f;
#pragma unroll
        for (int k = 0; k < DD; ++k) {
            float x = Xq[r * DD + k];   // wave-uniform address -> scalar load
            sa = fmaf(x, Wa[k * DD + j], sa);
            sb = fmaf(x, Wb[k * DD + j], sb);
        }
        int rb = r << 8;
        int gbase = rb + ((j >> 3) << 4) + (j & 7);
        YX16[gbase] = (_Float16)sa;       // ya fragment
        YX16[gbase + 8] = (_Float16)sb;   // yb fragment
        float xj = Xq[r * DD + j];
        YX16[rb + 128 + j] = (_Float16)xj;
        YX16[rb + 192 + j] = (_Float16)0.f;   // keep pad clean
        outXq[r * DD + j] = xj;               // replaces the outXq memcpy dispatch
        return;
    }

    // ---- bin role ----
    int e0 = blockIdx.x * CHUNK;
    int n = min(CHUNK, E - e0);
    if (n <= 0) return;

    for (int i = tid; i < NBUCK; i += 1024) hist[i] = 0;
    __syncthreads();

    unsigned p[4];
    int nv = 0;
    int i0 = tid * 4;
    if (i0 + 3 < n) {
        int4 u4 = *(const int4*)(u_idx + e0 + i0);
        int4 v4 = *(const int4*)(v_idx + e0 + i0);
        p[0] = ((unsigned)v4.x << 11) | (unsigned)u4.x;
        p[1] = ((unsigned)v4.y << 11) | (unsigned)u4.y;
        p[2] = ((unsigned)v4.z << 11) | (unsigned)u4.z;
        p[3] = ((unsigned)v4.w << 11) | (unsigned)u4.w;
        nv = 4;
    } else {
        for (int j = 0; j < 4; ++j) {
            if (i0 + j < n) {
                p[j] = ((unsigned)v_idx[e0 + i0 + j] << 11) | (unsigned)u_idx[e0 + i0 + j];
                ++nv;
            }
        }
    }
    for (int j = 0; j < nv; ++j) atomicAdd(&hist[p[j] >> 19], 1);
    __syncthreads();
    if (tid < 64) {   // wave 0: scan 512 buckets, 8 per lane
        int h[8], sum = 0;
#pragma unroll
        for (int j = 0; j < 8; ++j) { h[j] = hist[8 * tid + j]; sum += h[j]; }
        int incl = sum;
#pragma unroll
        for (int d = 1; d < 64; d <<= 1) {
            int y = __shfl_up(incl, d, 64);
            if (tid >= d) incl += y;
        }
        int excl = incl - sum;
#pragma unroll
        for (int j = 0; j < 8; ++j) { off[8 * tid + j] = excl; excl += h[j]; }
    }
    __syncthreads();
    // gcurP: one counter per 64B line (padding vs 16-way line sharing across XCDs)
    for (int i = tid; i < NBUCK; i += 1024) {
        base[i] = hist[i] ? atomicAdd(&gcurP[i << 4], hist[i]) : 0;
        cur[i] = off[i];
    }
    __syncthreads();
    for (int j = 0; j < nv; ++j) {
        int pos = atomicAdd(&cur[p[j] >> 19], 1);
        stage[pos] = p[j];
    }
    __syncthreads();
    for (int i = tid; i < n; i += 1024) {
        unsigned q = stage[i];
        int b = q >> 19;
        int idx = base[b] + (i - off[b]);
        if (idx < BCAP) gbuf[(size_t)b * BCAP + idx] = q;
    }
}

// DPP add helper (fused v_add_f32_dpp, bound_ctrl=true; all call sites have
// full groups active — edge validity is group-uniform, gated by a=0 selects).
template <int CTRL>
__device__ __forceinline__ float dpp_add(float x) {
    int xi = __builtin_bit_cast(int, x);
    int yi = __builtin_amdgcn_update_dpp(xi, xi, CTRL, 0xF, 0xF, true);
    return x + __builtin_bit_cast(float, yi);
}
// 8-lane all-reduce: quad xor1, quad xor2, then row_half_mirror (0x141:
// l <-> 7-l within each 8-lane half-row) completes the sum in ALL 8 lanes.
__device__ __forceinline__ float red8(float x) {
    x = dpp_add<0xB1>(x);    // quad_perm [1,0,3,2] : xor 1
    x = dpp_add<0x4E>(x);    // quad_perm [2,3,0,1] : xor 2
    x = dpp_add<0x141>(x);   // row_half_mirror
    return x;
}

// Fused LDS-sort + row phase. One block per coarse bucket (256 rows).
// Row phase v7: one row per wave, EIGHT 8-lane groups, 16 edges/iter
// (2 slots/group). Each lane covers 8 features (2x dwordx4 y-frags).
// Halves the per-edge share of the scalar ELU/sigmoid chain (the dominant
// issue cost at 8-cyc/transcendental) vs the 16-lane layout.
__global__ __launch_bounds__(1024, 2) void bucket_kernel(
        const float* __restrict__ Xq,
        const float* __restrict__ Xt,
        const _Float16* __restrict__ YX16,
        const float* __restrict__ ba,
        const float* __restrict__ bb,
        const int* __restrict__ gcurP,
        const unsigned* __restrict__ gbuf,
        const int* __restrict__ uc,
        float* __restrict__ outXt) {
    __shared__ unsigned short su[BCAP];
    __shared__ int hist[256], cur[256], rstart[257];
    int tid = threadIdx.x;
    int b = blockIdx.x;
    int n = min(gcurP[b << 4], BCAP);

    if (tid < 256) hist[tid] = 0;
    __syncthreads();
    for (int i = tid; i < n; i += 1024)
        atomicAdd(&hist[(gbuf[(size_t)b * BCAP + i] >> 11) & 255], 1);
    __syncthreads();
    if (tid < 64) {   // wave 0: scan 256 rows, 4 per lane
        int h0 = hist[4 * tid], h1 = hist[4 * tid + 1];
        int h2_ = hist[4 * tid + 2], h3 = hist[4 * tid + 3];
        int tot = h0 + h1 + h2_ + h3;
        int incl = tot;
#pragma unroll
        for (int d = 1; d < 64; d <<= 1) {
            int y = __shfl_up(incl, d, 64);
            if (tid >= d) incl += y;
        }
        int excl = incl - tot;
        rstart[4 * tid] = excl;             cur[4 * tid] = excl;
        rstart[4 * tid + 1] = excl + h0;    cur[4 * tid + 1] = excl + h0;
        rstart[4 * tid + 2] = excl + h0 + h1;       cur[4 * tid + 2] = excl + h0 + h1;
        rstart[4 * tid + 3] = excl + h0 + h1 + h2_; cur[4 * tid + 3] = excl + h0 + h1 + h2_;
        if (tid == 63) rstart[256] = excl + tot;
    }
    __syncthreads();
    for (int i = tid; i < n; i += 1024) {
        unsigned p = gbuf[(size_t)b * BCAP + i];
        int pos = atomicAdd(&cur[(p >> 11) & 255], 1);
        su[pos] = (unsigned short)(p & 0x7FFu);
    }
    __syncthreads();

    // ---- row phase ----
    int lane = tid & 63;
    int w = tid >> 6;          // wave 0..15
    int l8 = lane & 7;         // feature block: features [8*l8, 8*l8+8)
    int g8 = lane >> 3;        // group 0..7
    float ba0 = ba[0], bb0 = bb[0];

    for (int r = w; r < 256; r += 16) {
        int v = (b << 8) + r;
        int startr = rstart[r];
        int deg = rstart[r + 1] - startr;   // wave-uniform
        if (deg == 0) {
            if (lane < 8) {
                const float4* srcp;
                if (v >= NT - MM) {            // consensus row: Xq[uc[i]] (exact fp32)
                    srcp = (const float4*)(Xq + (size_t)uc[v - (NT - MM)] * DD);
                } else {
                    srcp = (const float4*)(Xt + (size_t)v * DD);
                }
                float4 o0 = srcp[lane * 2];
                float4 o1 = srcp[lane * 2 + 1];
                ((float4*)(outXt + (size_t)v * DD))[lane * 2] = o0;
                ((float4*)(outXt + (size_t)v * DD))[lane * 2 + 1] = o1;
            }
            continue;
        }
        // xt fragment: features [8*l8, 8*l8+8) as f32 (for output) + h2 (dots)
        float4 xtA = ((const float4*)(Xt + (size_t)v * DD))[l8 * 2];
        float4 xtB = ((const float4*)(Xt + (size_t)v * DD))[l8 * 2 + 1];
        h2 xh0, xh1, xh2, xh3;
        xh0.x = (_Float16)xtA.x; xh0.y = (_Float16)xtA.y;
        xh1.x = (_Float16)xtA.z; xh1.y = (_Float16)xtA.w;
        xh2.x = (_Float16)xtB.x; xh2.y = (_Float16)xtB.y;
        xh3.x = (_Float16)xtB.z; xh3.y = (_Float16)xtB.w;
        float4 accA = make_float4(0.f, 0.f, 0.f, 0.f);
        float4 accB = make_float4(0.f, 0.f, 0.f, 0.f);
        float s = 0.f;     // sum a        (softmax denominator)
        float s2 = 0.f;    // sum a*beta   (hoisted xt coefficient)
        for (int base = 0; base < deg; base += 16) {
            int e0 = base + g8;
            int e1 = base + 8 + g8;
            bool ok0 = e0 < deg, ok1 = e1 < deg;   // group-uniform
            int u0 = (int)su[startr + (ok0 ? e0 : 0)];
            int u1 = (int)su[startr + (ok1 ? e1 : 0)];
            const _Float16* P0 = YX16 + ((size_t)u0 << 8);
            const _Float16* P1 = YX16 + ((size_t)u1 << 8);
            float4 ya0 = *(const float4*)(P0 + (l8 << 4));       // ya[8l8..+7]
            float4 yb0 = *(const float4*)(P0 + (l8 << 4) + 8);   // yb[8l8..+7]
            float4 ya1 = *(const float4*)(P1 + (l8 << 4));
            float4 yb1 = *(const float4*)(P1 + (l8 << 4) + 8);
            float pa0 = fdot2(__builtin_bit_cast(h2, ya0.w), xh3,
                       fdot2(__builtin_bit_cast(h2, ya0.z), xh2,
                       fdot2(__builtin_bit_cast(h2, ya0.y), xh1,
                       fdot2(__builtin_bit_cast(h2, ya0.x), xh0, 0.f))));
            float pb0 = fdot2(__builtin_bit_cast(h2, yb0.w), xh3,
                       fdot2(__builtin_bit_cast(h2, yb0.z), xh2,
                       fdot2(__builtin_bit_cast(h2, yb0.y), xh1,
                       fdot2(__builtin_bit_cast(h2, yb0.x), xh0, 0.f))));
            float pa1 = fdot2(__builtin_bit_cast(h2, ya1.w), xh3,
                       fdot2(__builtin_bit_cast(h2, ya1.z), xh2,
                       fdot2(__builtin_bit_cast(h2, ya1.y), xh1,
                       fdot2(__builtin_bit_cast(h2, ya1.x), xh0, 0.f))));
            float pb1 = fdot2(__builtin_bit_cast(h2, yb1.w), xh3,
                       fdot2(__builtin_bit_cast(h2, yb1.z), xh2,
                       fdot2(__builtin_bit_cast(h2, yb1.y), xh1,
                       fdot2(__builtin_bit_cast(h2, yb1.x), xh0, 0.f))));
            pa0 = red8(pa0); pb0 = red8(pb0);
            pa1 = red8(pa1); pb1 = red8(pb1);
            float la0 = pa0 + ba0, la1 = pa1 + ba0;
            float t0 = __expf(la0), t1 = __expf(la1);
            float al0 = la0 > 0.f ? la0 : (t0 - 1.f);
            float al1 = la1 > 0.f ? la1 : (t1 - 1.f);
            float a0 = ok0 ? __expf(al0) : 0.f;   // gate tail edges to zero weight
            float a1 = ok1 ? __expf(al1) : 0.f;
            float be0 = __builtin_amdgcn_rcpf(1.f + __expf(-(pb0 + bb0)));
            float be1 = __builtin_amdgcn_rcpf(1.f + __expf(-(pb1 + bb0)));
            float c20 = a0 * be0, c21 = a1 * be1;   // a*beta  (xt coeff)
            float c10 = a0 - c20, c11 = a1 - c21;   // a*(1-beta) (xq coeff)
            float4 xv0 = *(const float4*)(P0 + 128 + (l8 << 3));   // xq16[8l8..+7]
            float4 xv1 = *(const float4*)(P1 + 128 + (l8 << 3));
            h2 q00 = __builtin_bit_cast(h2, xv0.x), q01 = __builtin_bit_cast(h2, xv0.y);
            h2 q02 = __builtin_bit_cast(h2, xv0.z), q03 = __builtin_bit_cast(h2, xv0.w);
            h2 q10 = __builtin_bit_cast(h2, xv1.x), q11 = __builtin_bit_cast(h2, xv1.y);
            h2 q12 = __builtin_bit_cast(h2, xv1.z), q13 = __builtin_bit_cast(h2, xv1.w);
            // v_fma_mix_f32: f16 source * f32 coeff + f32 acc
            accA.x = fmaf((float)q00.x, c10, accA.x);
            accA.y = fmaf((float)q00.y, c10, accA.y);
            accA.z = fmaf((float)q01.x, c10, accA.z);
            accA.w = fmaf((float)q01.y, c10, accA.w);
            accB.x = fmaf((float)q02.x, c10, accB.x);
            accB.y = fmaf((float)q02.y, c10, accB.y);
            accB.z = fmaf((float)q03.x, c10, accB.z);
            accB.w = fmaf((float)q03.y, c10, accB.w);
            accA.x = fmaf((float)q10.x, c11, accA.x);
            accA.y = fmaf((float)q10.y, c11, accA.y);
            accA.z = fmaf((float)q11.x, c11, accA.z);
            accA.w = fmaf((float)q11.y, c11, accA.w);
            accB.x = fmaf((float)q12.x, c11, accB.x);
            accB.y = fmaf((float)q12.y, c11, accB.y);
            accB.z = fmaf((float)q13.x, c11, accB.z);
            accB.w = fmaf((float)q13.y, c11, accB.w);
            s += a0 + a1;
            s2 += c20 + c21;
        }
        // combine 8 groups: xor8/16/32 give all lanes the totals.
#pragma unroll
        for (int offr = 8; offr <= 32; offr <<= 1) {
            accA.x += __shfl_xor(accA.x, offr, 64);
            accA.y += __shfl_xor(accA.y, offr, 64);
            accA.z += __shfl_xor(accA.z, offr, 64);
            accA.w += __shfl_xor(accA.w, offr, 64);
            accB.x += __shfl_xor(accB.x, offr, 64);
            accB.y += __shfl_xor(accB.y, offr, 64);
            accB.z += __shfl_xor(accB.z, offr, 64);
            accB.w += __shfl_xor(accB.w, offr, 64);
            s      += __shfl_xor(s, offr, 64);
            s2     += __shfl_xor(s2, offr, 64);
        }
        if (lane < 8) {    // lane l holds features [8l, 8l+8) (l8 == lane)
            float inv = __builtin_amdgcn_rcpf(s);
            float4 oA, oB;
            oA.x = fmaf(s2, xtA.x, accA.x) * inv;
            oA.y = fmaf(s2, xtA.y, accA.y) * inv;
            oA.z = fmaf(s2, xtA.z, accA.z) * inv;
            oA.w = fmaf(s2, xtA.w, accA.w) * inv;
            oB.x = fmaf(s2, xtB.x, accB.x) * inv;
            oB.y = fmaf(s2, xtB.y, accB.y) * inv;
            oB.z = fmaf(s2, xtB.z, accB.z) * inv;
            oB.w = fmaf(s2, xtB.w, accB.w) * inv;
            ((float4*)(outXt + (size_t)v * DD))[lane * 2] = oA;
            ((float4*)(outXt + (size_t)v * DD))[lane * 2 + 1] = oB;
        }
    }
}

extern "C" void kernel_launch(void* const* d_in, const int* in_sizes, int n_in,
                              void* d_out, int out_size, void* d_ws, size_t ws_size,
                              hipStream_t stream) {
    const float* Xq = (const float*)d_in[0];
    const float* Xt = (const float*)d_in[1];
    const float* Wa = (const float*)d_in[2];
    const float* ba = (const float*)d_in[3];
    const float* Wb = (const float*)d_in[4];
    const float* bb = (const float*)d_in[5];
    const int* u_idx = (const int*)d_in[6];
    const int* v_idx = (const int*)d_in[7];
    const int* uc = (const int*)d_in[8];
    const int* vc = (const int*)d_in[9];
    const int E = in_sizes[6];
    (void)vc;

    float* out = (float*)d_out;
    float* outXq = out;                 // NQ*DD
    float* outXt = out + NQ * DD;       // NT*DD

    char* ws = (char*)d_ws;
    _Float16* YX16 = (_Float16*)ws;   ws += (size_t)NQ * 256 * sizeof(_Float16);       // 1M
    int* gcurP = (int*)ws;            ws += (size_t)NBUCK * 16 * sizeof(int);          // 32K
    ws = (char*)(((size_t)ws + 255) & ~(size_t)255);
    unsigned* gbuf = (unsigned*)ws;   ws += (size_t)NBUCK * BCAP * sizeof(unsigned);   // 9.4M

    hipMemsetAsync(gcurP, 0, (size_t)NBUCK * 16 * sizeof(int), stream);

    int nchunks = (E + CHUNK - 1) / CHUNK;
    bin_yq_kernel<<<nchunks + NQ / 16, 1024, 0, stream>>>(
        u_idx, v_idx, gcurP, gbuf, Xq, Wa, Wb, YX16, outXq, E);

    bucket_kernel<<<NBUCK, 1024, 0, stream>>>(Xq, Xt, YX16, ba, bb, gcurP, gbuf,
                                              uc, outXt);
}